// Round 1
// baseline (8906.435 us; speedup 1.0000x reference)
//
#include <hip/hip_runtime.h>
#include <math.h>
#include <stdint.h>

// ---------------------------------------------------------------------------
// SigAutoEncoder on MI355X.
// Heavy part: decoder = 9120 strictly-sequential GRU steps (h carried through
// 96 outer x 95 inner scan steps). One workgroup per batch element (16 CUs),
// recurrent matmul done with mfma_f32_16x16x32_bf16, Wh resident in VGPRs.
// ---------------------------------------------------------------------------

namespace {

constexpr int B  = 16;    // batch
constexpr int T  = 96;    // seq len == input dim
constexpr int C  = 64;    // conv channels
constexpr int L1 = 93;    // conv1 out length
constexpr int LP = 23;    // pooled length
constexpr int F  = 20;    // conv2 out length (GRU input dim)
constexpr int HE = 96;    // encoder GRU hidden
constexpr int GE = 288;   // 3*HE
constexpr int HD = 192;   // decoder hidden
constexpr int GD = 576;   // 3*HD
constexpr int SD = 95;    // decoder inner steps

// workspace layout (in floats)
constexpr int WS_HENC = 0;                   // B*C*F = 20480
constexpr int WS_Z    = WS_HENC + B * C * F; // 3072
constexpr int WS_XW   = WS_Z + B * HD;       // B*T*GD = 884736
constexpr int WS_WHB  = WS_XW + B * T * GD;  // GD*HD bf16 = 55296 floats

// d_out layout (floats): out0 (B*T*T) | mu (B*HD) | logvar (B*HD)
constexpr int OUT_MU = B * T * T;            // 147456
constexpr int OUT_LV = OUT_MU + B * HD;      // 150528

typedef short bf16x8 __attribute__((ext_vector_type(8)));   // 8 bf16 = 4 VGPRs
typedef float f32x4  __attribute__((ext_vector_type(4)));

__device__ __forceinline__ float sigmf(float x) { return 1.0f / (1.0f + expf(-x)); }

__device__ __forceinline__ unsigned short f2bf(float x) {  // RNE f32->bf16
  unsigned u = __builtin_bit_cast(unsigned, x);
  u += 0x7FFFu + ((u >> 16) & 1u);
  return (unsigned short)(u >> 16);
}

// ---------------------------------------------------------------------------
// Encoder: conv1(relu) -> maxpool4 -> conv2(relu). One block per batch.
// ---------------------------------------------------------------------------
__global__ __launch_bounds__(256) void enc_conv(
    const float* __restrict__ input, const float* __restrict__ Wc1,
    const float* __restrict__ bc1, const float* __restrict__ Wc2,
    const float* __restrict__ bc2, float* __restrict__ h_enc) {
  __shared__ float xin[T * T];   // 9216 f
  __shared__ float y1[C * L1];   // 5952 f
  const int b = blockIdx.x;
  for (int i = threadIdx.x; i < T * T; i += 256) xin[i] = input[b * T * T + i];
  __syncthreads();
  // conv1 + relu
  for (int idx = threadIdx.x; idx < C * L1; idx += 256) {
    const int o = idx / L1, t = idx - o * L1;
    const float* w = Wc1 + o * (T * 4);
    float acc = bc1[o];
#pragma unroll 8
    for (int i = 0; i < T; ++i) {
      float4 wv = *reinterpret_cast<const float4*>(w + i * 4);
      const float* xp = xin + i * T + t;
      acc = fmaf(wv.x, xp[0], acc);
      acc = fmaf(wv.y, xp[1], acc);
      acc = fmaf(wv.z, xp[2], acc);
      acc = fmaf(wv.w, xp[3], acc);
    }
    y1[idx] = fmaxf(acc, 0.0f);
  }
  __syncthreads();
  // maxpool k=4 s=4, result into xin region (conv1 inputs no longer needed)
  float* pl = xin;  // C*LP = 1472 floats
  for (int idx = threadIdx.x; idx < C * LP; idx += 256) {
    const int o = idx / LP, t = idx - o * LP;
    const float* yp = y1 + o * L1 + 4 * t;
    pl[idx] = fmaxf(fmaxf(yp[0], yp[1]), fmaxf(yp[2], yp[3]));
  }
  __syncthreads();
  // conv2 + relu
  for (int idx = threadIdx.x; idx < C * F; idx += 256) {
    const int o = idx / F, t = idx - o * F;
    const float* w = Wc2 + o * (C * 4);
    float acc = bc2[o];
#pragma unroll 8
    for (int i = 0; i < C; ++i) {
      float4 wv = *reinterpret_cast<const float4*>(w + i * 4);
      const float* xp = pl + i * LP + t;
      acc = fmaf(wv.x, xp[0], acc);
      acc = fmaf(wv.y, xp[1], acc);
      acc = fmaf(wv.z, xp[2], acc);
      acc = fmaf(wv.w, xp[3], acc);
    }
    h_enc[b * (C * F) + idx] = fmaxf(acc, 0.0f);
  }
}

// ---------------------------------------------------------------------------
// Encoder BiGRU chains. Block = (chain 0..3) x (batch 0..15). 320 threads.
// Thread g<288 holds Wi row (20f) + Wh row (96f) in VGPRs. Only the FINAL
// hidden of each direction is needed (mu/logvar concat).
// chain: 0=muf(fwd) 1=mub(bwd) 2=sgf(fwd) 3=sgb(bwd)
// ---------------------------------------------------------------------------
__global__ __launch_bounds__(320) void enc_gru(
    const float* __restrict__ h_enc,
    const float* __restrict__ Wi0, const float* __restrict__ Wh0,
    const float* __restrict__ bi0, const float* __restrict__ bh0,
    const float* __restrict__ Wi1, const float* __restrict__ Wh1,
    const float* __restrict__ bi1, const float* __restrict__ bh1,
    const float* __restrict__ Wi2, const float* __restrict__ Wh2,
    const float* __restrict__ bi2, const float* __restrict__ bh2,
    const float* __restrict__ Wi3, const float* __restrict__ Wh3,
    const float* __restrict__ bi3, const float* __restrict__ bh3,
    float* __restrict__ out) {
  const int chain = blockIdx.x >> 4;
  const int b = blockIdx.x & 15;
  const float *Wi, *Wh, *bi, *bh;
  if (chain == 0)      { Wi = Wi0; Wh = Wh0; bi = bi0; bh = bh0; }
  else if (chain == 1) { Wi = Wi1; Wh = Wh1; bi = bi1; bh = bh1; }
  else if (chain == 2) { Wi = Wi2; Wh = Wh2; bi = bi2; bh = bh2; }
  else                 { Wi = Wi3; Wh = Wh3; bi = bi3; bh = bh3; }
  const bool fwd = (chain & 1) == 0;
  const int off = ((chain >> 1) ? OUT_LV : OUT_MU) + b * HD + (fwd ? 0 : HE);

  __shared__ float xall[C * F];  // 1280
  __shared__ float h[HE];
  __shared__ float gx[GE], ghs[GE];

  const int tid = threadIdx.x;
  for (int i = tid; i < C * F; i += 320) xall[i] = h_enc[b * (C * F) + i];
  if (tid < HE) h[tid] = 0.0f;

  float wi[F], wh[HE], big = 0.0f, bhg = 0.0f;
  if (tid < GE) {
#pragma unroll
    for (int d = 0; d < F; ++d) wi[d] = Wi[tid * F + d];
#pragma unroll
    for (int k = 0; k < HE; ++k) wh[k] = Wh[tid * HE + k];
    big = bi[tid];
    bhg = bh[tid];
  }
  __syncthreads();

  for (int s = 0; s < C; ++s) {
    const int se = fwd ? s : (C - 1 - s);
    if (tid < GE) {
      const float* xr = xall + se * F;
      float ax = big, ah = bhg;
#pragma unroll
      for (int d = 0; d < F; ++d) ax = fmaf(wi[d], xr[d], ax);
#pragma unroll
      for (int k = 0; k < HE; ++k) ah = fmaf(wh[k], h[k], ah);
      gx[tid] = ax;
      ghs[tid] = ah;
    }
    __syncthreads();
    if (tid < HE) {
      const float r  = sigmf(gx[tid] + ghs[tid]);
      const float zg = sigmf(gx[HE + tid] + ghs[HE + tid]);
      const float n  = tanhf(fmaf(r, ghs[2 * HE + tid], gx[2 * HE + tid]));
      h[tid] = fmaf(zg, h[tid] - n, n);  // (1-z)n + z h
    }
    __syncthreads();
  }
  if (tid < HE) out[off + tid] = h[tid];
}

// ---------------------------------------------------------------------------
// z = mu + eps * exp(0.5*logvar), eps = jax.random.normal(key(42),(16,192)).
// Exact threefry-2x32 (ks0=0, ks1=42) + JAX uniform mapping + XLA erfinv.
// ---------------------------------------------------------------------------
__device__ __forceinline__ uint32_t rotl32(uint32_t v, int d) {
  return (v << d) | (v >> (32 - d));
}

__device__ __forceinline__ float erfinv32(float x) {  // XLA ErfInv32 (Giles)
  float w = -log1pf(-x * x);
  float p;
  if (w < 5.0f) {
    w -= 2.5f;
    p = 2.81022636e-08f;
    p = fmaf(p, w, 3.43273939e-07f);
    p = fmaf(p, w, -3.5233877e-06f);
    p = fmaf(p, w, -4.39150654e-06f);
    p = fmaf(p, w, 0.00021858087f);
    p = fmaf(p, w, -0.00125372503f);
    p = fmaf(p, w, -0.00417768164f);
    p = fmaf(p, w, 0.246640727f);
    p = fmaf(p, w, 1.50140941f);
  } else {
    w = sqrtf(w) - 3.0f;
    p = -0.000200214257f;
    p = fmaf(p, w, 0.000100950558f);
    p = fmaf(p, w, 0.00134934322f);
    p = fmaf(p, w, -0.00367342844f);
    p = fmaf(p, w, 0.00573950773f);
    p = fmaf(p, w, -0.0076224613f);
    p = fmaf(p, w, 0.00943887047f);
    p = fmaf(p, w, 1.00167406f);
    p = fmaf(p, w, 2.83297682f);
  }
  return p * x;
}

__global__ __launch_bounds__(256) void z_kernel(const float* __restrict__ dout,
                                                float* __restrict__ z) {
  const int p = blockIdx.x * 256 + threadIdx.x;
  if (p >= 1536) return;
  const uint32_t ks0 = 0u, ks1 = 42u;
  const uint32_t ks2 = 0x1BD11BDAu ^ ks0 ^ ks1;
  uint32_t x0 = (uint32_t)p + ks0;
  uint32_t x1 = (uint32_t)(p + 1536) + ks1;
  // 20 rounds of threefry-2x32
  x0 += x1; x1 = rotl32(x1, 13) ^ x0;
  x0 += x1; x1 = rotl32(x1, 15) ^ x0;
  x0 += x1; x1 = rotl32(x1, 26) ^ x0;
  x0 += x1; x1 = rotl32(x1, 6)  ^ x0;
  x0 += ks1; x1 += ks2 + 1u;
  x0 += x1; x1 = rotl32(x1, 17) ^ x0;
  x0 += x1; x1 = rotl32(x1, 29) ^ x0;
  x0 += x1; x1 = rotl32(x1, 16) ^ x0;
  x0 += x1; x1 = rotl32(x1, 24) ^ x0;
  x0 += ks2; x1 += ks0 + 2u;
  x0 += x1; x1 = rotl32(x1, 13) ^ x0;
  x0 += x1; x1 = rotl32(x1, 15) ^ x0;
  x0 += x1; x1 = rotl32(x1, 26) ^ x0;
  x0 += x1; x1 = rotl32(x1, 6)  ^ x0;
  x0 += ks0; x1 += ks1 + 3u;
  x0 += x1; x1 = rotl32(x1, 17) ^ x0;
  x0 += x1; x1 = rotl32(x1, 29) ^ x0;
  x0 += x1; x1 = rotl32(x1, 16) ^ x0;
  x0 += x1; x1 = rotl32(x1, 24) ^ x0;
  x0 += ks1; x1 += ks2 + 4u;
  x0 += x1; x1 = rotl32(x1, 13) ^ x0;
  x0 += x1; x1 = rotl32(x1, 15) ^ x0;
  x0 += x1; x1 = rotl32(x1, 26) ^ x0;
  x0 += x1; x1 = rotl32(x1, 6)  ^ x0;
  x0 += ks2; x1 += ks0 + 5u;

  const float* mu = dout + OUT_MU;
  const float* lv = dout + OUT_LV;
  const float lo = -0.99999994f;  // nextafter(-1, 0) in f32
#pragma unroll
  for (int half = 0; half < 2; ++half) {
    const uint32_t bits = half ? x1 : x0;
    const int e = half ? (p + 1536) : p;
    const float f = __builtin_bit_cast(float, (bits >> 9) | 0x3F800000u) - 1.0f;
    const float u = fmaxf(lo, fmaf(f, 2.0f, lo));  // scale (1-lo) rounds to 2.0f
    const float eps = 1.41421356f * erfinv32(u);
    z[e] = fmaf(eps, expf(0.5f * lv[e]), mu[e]);
  }
}

// ---------------------------------------------------------------------------
// XW[b,r,:] = input[b,r,:] @ Wi_d.T + bi_d   (B*T rows, GD gates)
// ---------------------------------------------------------------------------
__global__ __launch_bounds__(192) void dec_xw(const float* __restrict__ input,
                                              const float* __restrict__ Wi,
                                              const float* __restrict__ bi,
                                              float* __restrict__ XW) {
  const int br = blockIdx.x;  // b*T + r
  __shared__ float xrow[T];
  if (threadIdx.x < T) xrow[threadIdx.x] = input[br * T + threadIdx.x];
  __syncthreads();
  for (int g = threadIdx.x; g < GD; g += 192) {
    const float* w = Wi + g * T;
    float acc = bi[g];
#pragma unroll 8
    for (int d = 0; d < T; ++d) acc = fmaf(w[d], xrow[d], acc);
    XW[br * GD + g] = acc;
  }
}

__global__ __launch_bounds__(256) void wh_to_bf16(const float* __restrict__ w,
                                                  unsigned short* __restrict__ o) {
  const int i = blockIdx.x * 256 + threadIdx.x;
  if (i < GD * HD) o[i] = f2bf(w[i]);
}

// ---------------------------------------------------------------------------
// Decoder: one block per batch (512 threads = 8 waves). 9120 sequential GRU
// steps. Wh (576x192 bf16) lives in VGPRs as MFMA B-fragments: waves 0-3 own
// 5 N-tiles, waves 4-7 own 4 (36 tiles of 16 gates). h broadcast in LDS (f32
// master + bf16 copy); M=1 usage of 16x16x32 MFMA (A rows replicated with h).
// ---------------------------------------------------------------------------
__global__ __launch_bounds__(512) void decoder(
    const float* __restrict__ XW, const unsigned short* __restrict__ WhB,
    const float* __restrict__ bh, const float* __restrict__ z,
    const float* __restrict__ Wl, const float* __restrict__ bl,
    float* __restrict__ dout) {
  const int b = blockIdx.x;
  const int tid = threadIdx.x;
  const int lane = tid & 63;
  const int w = tid >> 6;
  const int nt = (w < 4) ? 5 : 4;            // tiles owned by this wave
  const int tb = (w < 4) ? 5 * w : 4 * w + 4; // first tile index
  const int col = lane & 15;
  const int g4 = lane >> 4;

  __shared__ float hf[HD];
  __shared__ alignas(16) unsigned short hb[HD];
  __shared__ float ghs[GD];

  // B fragments: lane holds Wh[gate = 16*tile + col][32*kk + 8*g4 + j], j=0..7
  bf16x8 bfr[5][6];
  float bhr[5];
#pragma unroll
  for (int t = 0; t < 5; ++t) {
    if (t < nt) {
      const int gate = 16 * (tb + t) + col;
      const uint4* wp = reinterpret_cast<const uint4*>(WhB + gate * HD);
#pragma unroll
      for (int kk = 0; kk < 6; ++kk)
        bfr[t][kk] = __builtin_bit_cast(bf16x8, wp[kk * 4 + g4]);
      bhr[t] = bh[gate];
    }
  }

  if (tid < HD) {
    const float hz = z[b * HD + tid];
    hf[tid] = hz;
    hb[tid] = f2bf(hz);
  }
  __syncthreads();

  const uint4* hbv = reinterpret_cast<const uint4*>(hb);
  const f32x4 zero4 = {0.0f, 0.0f, 0.0f, 0.0f};

  for (int i = 0; i < T; ++i) {
    for (int s = 0; s < SD; ++s) {
      const int rr = s + (s >= i ? 1 : 0);  // leave-one-out row index
      float xr = 0.0f, xz = 0.0f, xn = 0.0f;
      if (tid < HD) {  // prefetch x-gates (independent of h -> overlaps MFMA)
        const float* xwrow = XW + (b * T + rr) * GD;
        xr = xwrow[tid];
        xz = xwrow[HD + tid];
        xn = xwrow[2 * HD + tid];
      }
      // A fragments: broadcast h (all 16 rows identical -> row mapping moot)
      bf16x8 a[6];
#pragma unroll
      for (int kk = 0; kk < 6; ++kk)
        a[kk] = __builtin_bit_cast(bf16x8, hbv[kk * 4 + g4]);
      f32x4 acc[5];
#pragma unroll
      for (int t = 0; t < 5; ++t) acc[t] = zero4;
#pragma unroll
      for (int kk = 0; kk < 6; ++kk) {
#pragma unroll
        for (int t = 0; t < 5; ++t) {
          if (t < nt)
            acc[t] = __builtin_amdgcn_mfma_f32_16x16x32_bf16(a[kk], bfr[t][kk],
                                                             acc[t], 0, 0, 0);
        }
      }
      // D row 0, col = lane&15 -> gate preacts; lanes 0-15 publish
      if (lane < 16) {
#pragma unroll
        for (int t = 0; t < 5; ++t)
          if (t < nt) ghs[16 * (tb + t) + lane] = acc[t][0] + bhr[t];
      }
      __syncthreads();
      if (tid < HD) {
        const float gr = ghs[tid], gz = ghs[HD + tid], gn = ghs[2 * HD + tid];
        const float r  = sigmf(xr + gr);
        const float zg = sigmf(xz + gz);
        const float n  = tanhf(fmaf(r, gn, xn));
        const float hnew = fmaf(zg, hf[tid] - n, n);  // (1-z)n + z h
        hf[tid] = hnew;
        hb[tid] = f2bf(hnew);
      }
      __syncthreads();
    }
    // out_i = h @ Wl.T + bl
    if (tid < T) {
      const float* wl = Wl + tid * HD;
      float acc = bl[tid];
#pragma unroll 8
      for (int k = 0; k < HD; ++k) acc = fmaf(wl[k], hf[k], acc);
      dout[(b * T + i) * T + tid] = acc;
    }
    __syncthreads();
  }
}

}  // namespace

// ---------------------------------------------------------------------------
extern "C" void kernel_launch(void* const* d_in, const int* in_sizes, int n_in,
                              void* d_out, int out_size, void* d_ws,
                              size_t ws_size, hipStream_t stream) {
  const float* input  = (const float*)d_in[0];
  const float* Wc1    = (const float*)d_in[1];
  const float* bc1    = (const float*)d_in[2];
  const float* Wc2    = (const float*)d_in[3];
  const float* bc2    = (const float*)d_in[4];
  const float* Wi_muf = (const float*)d_in[5];
  const float* Wh_muf = (const float*)d_in[6];
  const float* bi_muf = (const float*)d_in[7];
  const float* bh_muf = (const float*)d_in[8];
  const float* Wi_mub = (const float*)d_in[9];
  const float* Wh_mub = (const float*)d_in[10];
  const float* bi_mub = (const float*)d_in[11];
  const float* bh_mub = (const float*)d_in[12];
  const float* Wi_sgf = (const float*)d_in[13];
  const float* Wh_sgf = (const float*)d_in[14];
  const float* bi_sgf = (const float*)d_in[15];
  const float* bh_sgf = (const float*)d_in[16];
  const float* Wi_sgb = (const float*)d_in[17];
  const float* Wh_sgb = (const float*)d_in[18];
  const float* bi_sgb = (const float*)d_in[19];
  const float* bh_sgb = (const float*)d_in[20];
  const float* Wi_d   = (const float*)d_in[21];
  const float* Wh_d   = (const float*)d_in[22];
  const float* bi_d   = (const float*)d_in[23];
  const float* bh_d   = (const float*)d_in[24];
  const float* Wl     = (const float*)d_in[25];
  const float* bl     = (const float*)d_in[26];

  float* ws = (float*)d_ws;
  float* h_enc = ws + WS_HENC;
  float* zbuf  = ws + WS_Z;
  float* XW    = ws + WS_XW;
  unsigned short* WhB = (unsigned short*)(ws + WS_WHB);
  float* out = (float*)d_out;

  enc_conv<<<B, 256, 0, stream>>>(input, Wc1, bc1, Wc2, bc2, h_enc);
  enc_gru<<<64, 320, 0, stream>>>(h_enc, Wi_muf, Wh_muf, bi_muf, bh_muf,
                                  Wi_mub, Wh_mub, bi_mub, bh_mub,
                                  Wi_sgf, Wh_sgf, bi_sgf, bh_sgf,
                                  Wi_sgb, Wh_sgb, bi_sgb, bh_sgb, out);
  z_kernel<<<6, 256, 0, stream>>>(out, zbuf);
  dec_xw<<<B * T, 192, 0, stream>>>(input, Wi_d, bi_d, XW);
  wh_to_bf16<<<(GD * HD + 255) / 256, 256, 0, stream>>>(Wh_d, WhB);
  decoder<<<B, 512, 0, stream>>>(XW, WhB, bh_d, zbuf, Wl, bl, out);
}

// Round 2
// 6306.632 us; speedup vs baseline: 1.4122x; 1.4122x over previous
//
#include <hip/hip_runtime.h>
#include <math.h>
#include <stdint.h>

// ---------------------------------------------------------------------------
// SigAutoEncoder on MI355X.
// Decoder = 9120 strictly-sequential GRU steps. One block (12 waves) per
// batch. Wave w owns gate-tile triplet {w, 12+w, 24+w} so each lane holds the
// r/z/n preactivations for one h-index in registers after the MFMAs ->
// in-register gate math, ONE barrier per step, double-buffered h in LDS.
// Matrix floor: 216 x mfma_16x16x32 per step per CU ~= 1048 cy.
// ---------------------------------------------------------------------------

namespace {

constexpr int B  = 16;    // batch
constexpr int T  = 96;    // seq len == input dim
constexpr int C  = 64;    // conv channels
constexpr int L1 = 93;    // conv1 out length
constexpr int LP = 23;    // pooled length
constexpr int F  = 20;    // conv2 out length (GRU input dim)
constexpr int HE = 96;    // encoder GRU hidden
constexpr int GE = 288;   // 3*HE
constexpr int HD = 192;   // decoder hidden
constexpr int GD = 576;   // 3*HD
constexpr int SD = 95;    // decoder inner steps

// workspace layout (in floats)
constexpr int WS_HENC = 0;                   // B*C*F
constexpr int WS_Z    = WS_HENC + B * C * F;
constexpr int WS_XW   = WS_Z + B * HD;       // B*T*GD
constexpr int WS_WHH  = WS_XW + B * T * GD;  // GD*HD f16 = 55296 floats

// d_out layout (floats): out0 (B*T*T) | mu (B*HD) | logvar (B*HD)
constexpr int OUT_MU = B * T * T;
constexpr int OUT_LV = OUT_MU + B * HD;

typedef _Float16 half8 __attribute__((ext_vector_type(8)));  // 4 VGPRs
typedef float f32x4  __attribute__((ext_vector_type(4)));

constexpr float LOG2E  = 1.4426950408889634f;
constexpr float LOG2E2 = 2.8853900817779268f;

__device__ __forceinline__ float sigmf(float x) { return 1.0f / (1.0f + expf(-x)); }

// fast sigmoid/tanh on v_exp_f32 + v_rcp_f32 (rel err ~1e-6, tolerance 4.75e-2)
__device__ __forceinline__ float fsig(float v) {
  float u = __builtin_amdgcn_exp2f(v * -LOG2E);
  return __builtin_amdgcn_rcpf(1.0f + u);
}
__device__ __forceinline__ float ftanh(float v) {
  float u = __builtin_amdgcn_exp2f(v * LOG2E2);
  return fmaf(-2.0f, __builtin_amdgcn_rcpf(1.0f + u), 1.0f);
}

// ---------------------------------------------------------------------------
// Encoder: conv1(relu) -> maxpool4 -> conv2(relu). One block per batch.
// ---------------------------------------------------------------------------
__global__ __launch_bounds__(256) void enc_conv(
    const float* __restrict__ input, const float* __restrict__ Wc1,
    const float* __restrict__ bc1, const float* __restrict__ Wc2,
    const float* __restrict__ bc2, float* __restrict__ h_enc) {
  __shared__ float xin[T * T];
  __shared__ float y1[C * L1];
  const int b = blockIdx.x;
  for (int i = threadIdx.x; i < T * T; i += 256) xin[i] = input[b * T * T + i];
  __syncthreads();
  for (int idx = threadIdx.x; idx < C * L1; idx += 256) {
    const int o = idx / L1, t = idx - o * L1;
    const float* w = Wc1 + o * (T * 4);
    float acc = bc1[o];
#pragma unroll 8
    for (int i = 0; i < T; ++i) {
      float4 wv = *reinterpret_cast<const float4*>(w + i * 4);
      const float* xp = xin + i * T + t;
      acc = fmaf(wv.x, xp[0], acc);
      acc = fmaf(wv.y, xp[1], acc);
      acc = fmaf(wv.z, xp[2], acc);
      acc = fmaf(wv.w, xp[3], acc);
    }
    y1[idx] = fmaxf(acc, 0.0f);
  }
  __syncthreads();
  float* pl = xin;
  for (int idx = threadIdx.x; idx < C * LP; idx += 256) {
    const int o = idx / LP, t = idx - o * LP;
    const float* yp = y1 + o * L1 + 4 * t;
    pl[idx] = fmaxf(fmaxf(yp[0], yp[1]), fmaxf(yp[2], yp[3]));
  }
  __syncthreads();
  for (int idx = threadIdx.x; idx < C * F; idx += 256) {
    const int o = idx / F, t = idx - o * F;
    const float* w = Wc2 + o * (C * 4);
    float acc = bc2[o];
#pragma unroll 8
    for (int i = 0; i < C; ++i) {
      float4 wv = *reinterpret_cast<const float4*>(w + i * 4);
      const float* xp = pl + i * LP + t;
      acc = fmaf(wv.x, xp[0], acc);
      acc = fmaf(wv.y, xp[1], acc);
      acc = fmaf(wv.z, xp[2], acc);
      acc = fmaf(wv.w, xp[3], acc);
    }
    h_enc[b * (C * F) + idx] = fmaxf(acc, 0.0f);
  }
}

// ---------------------------------------------------------------------------
// Encoder BiGRU chains. Block = (chain 0..3) x (batch 0..15). 320 threads.
// ---------------------------------------------------------------------------
__global__ __launch_bounds__(320) void enc_gru(
    const float* __restrict__ h_enc,
    const float* __restrict__ Wi0, const float* __restrict__ Wh0,
    const float* __restrict__ bi0, const float* __restrict__ bh0,
    const float* __restrict__ Wi1, const float* __restrict__ Wh1,
    const float* __restrict__ bi1, const float* __restrict__ bh1,
    const float* __restrict__ Wi2, const float* __restrict__ Wh2,
    const float* __restrict__ bi2, const float* __restrict__ bh2,
    const float* __restrict__ Wi3, const float* __restrict__ Wh3,
    const float* __restrict__ bi3, const float* __restrict__ bh3,
    float* __restrict__ out) {
  const int chain = blockIdx.x >> 4;
  const int b = blockIdx.x & 15;
  const float *Wi, *Wh, *bi, *bh;
  if (chain == 0)      { Wi = Wi0; Wh = Wh0; bi = bi0; bh = bh0; }
  else if (chain == 1) { Wi = Wi1; Wh = Wh1; bi = bi1; bh = bh1; }
  else if (chain == 2) { Wi = Wi2; Wh = Wh2; bi = bi2; bh = bh2; }
  else                 { Wi = Wi3; Wh = Wh3; bi = bi3; bh = bh3; }
  const bool fwd = (chain & 1) == 0;
  const int off = ((chain >> 1) ? OUT_LV : OUT_MU) + b * HD + (fwd ? 0 : HE);

  __shared__ float xall[C * F];
  __shared__ float h[HE];
  __shared__ float gx[GE], ghs[GE];

  const int tid = threadIdx.x;
  for (int i = tid; i < C * F; i += 320) xall[i] = h_enc[b * (C * F) + i];
  if (tid < HE) h[tid] = 0.0f;

  float wi[F], wh[HE], big = 0.0f, bhg = 0.0f;
  if (tid < GE) {
#pragma unroll
    for (int d = 0; d < F; ++d) wi[d] = Wi[tid * F + d];
#pragma unroll
    for (int k = 0; k < HE; ++k) wh[k] = Wh[tid * HE + k];
    big = bi[tid];
    bhg = bh[tid];
  }
  __syncthreads();

  for (int s = 0; s < C; ++s) {
    const int se = fwd ? s : (C - 1 - s);
    if (tid < GE) {
      const float* xr = xall + se * F;
      float ax = big, ah = bhg;
#pragma unroll
      for (int d = 0; d < F; ++d) ax = fmaf(wi[d], xr[d], ax);
#pragma unroll
      for (int k = 0; k < HE; ++k) ah = fmaf(wh[k], h[k], ah);
      gx[tid] = ax;
      ghs[tid] = ah;
    }
    __syncthreads();
    if (tid < HE) {
      const float r  = sigmf(gx[tid] + ghs[tid]);
      const float zg = sigmf(gx[HE + tid] + ghs[HE + tid]);
      const float n  = tanhf(fmaf(r, ghs[2 * HE + tid], gx[2 * HE + tid]));
      h[tid] = fmaf(zg, h[tid] - n, n);
    }
    __syncthreads();
  }
  if (tid < HE) out[off + tid] = h[tid];
}

// ---------------------------------------------------------------------------
// z = mu + eps * exp(0.5*logvar), eps = jax.random.normal(key(42),(16,192)).
// ---------------------------------------------------------------------------
__device__ __forceinline__ uint32_t rotl32(uint32_t v, int d) {
  return (v << d) | (v >> (32 - d));
}

__device__ __forceinline__ float erfinv32(float x) {  // XLA ErfInv32 (Giles)
  float w = -log1pf(-x * x);
  float p;
  if (w < 5.0f) {
    w -= 2.5f;
    p = 2.81022636e-08f;
    p = fmaf(p, w, 3.43273939e-07f);
    p = fmaf(p, w, -3.5233877e-06f);
    p = fmaf(p, w, -4.39150654e-06f);
    p = fmaf(p, w, 0.00021858087f);
    p = fmaf(p, w, -0.00125372503f);
    p = fmaf(p, w, -0.00417768164f);
    p = fmaf(p, w, 0.246640727f);
    p = fmaf(p, w, 1.50140941f);
  } else {
    w = sqrtf(w) - 3.0f;
    p = -0.000200214257f;
    p = fmaf(p, w, 0.000100950558f);
    p = fmaf(p, w, 0.00134934322f);
    p = fmaf(p, w, -0.00367342844f);
    p = fmaf(p, w, 0.00573950773f);
    p = fmaf(p, w, -0.0076224613f);
    p = fmaf(p, w, 0.00943887047f);
    p = fmaf(p, w, 1.00167406f);
    p = fmaf(p, w, 2.83297682f);
  }
  return p * x;
}

__global__ __launch_bounds__(256) void z_kernel(const float* __restrict__ dout,
                                                float* __restrict__ z) {
  const int p = blockIdx.x * 256 + threadIdx.x;
  if (p >= 1536) return;
  const uint32_t ks0 = 0u, ks1 = 42u;
  const uint32_t ks2 = 0x1BD11BDAu ^ ks0 ^ ks1;
  uint32_t x0 = (uint32_t)p + ks0;
  uint32_t x1 = (uint32_t)(p + 1536) + ks1;
  x0 += x1; x1 = rotl32(x1, 13) ^ x0;
  x0 += x1; x1 = rotl32(x1, 15) ^ x0;
  x0 += x1; x1 = rotl32(x1, 26) ^ x0;
  x0 += x1; x1 = rotl32(x1, 6)  ^ x0;
  x0 += ks1; x1 += ks2 + 1u;
  x0 += x1; x1 = rotl32(x1, 17) ^ x0;
  x0 += x1; x1 = rotl32(x1, 29) ^ x0;
  x0 += x1; x1 = rotl32(x1, 16) ^ x0;
  x0 += x1; x1 = rotl32(x1, 24) ^ x0;
  x0 += ks2; x1 += ks0 + 2u;
  x0 += x1; x1 = rotl32(x1, 13) ^ x0;
  x0 += x1; x1 = rotl32(x1, 15) ^ x0;
  x0 += x1; x1 = rotl32(x1, 26) ^ x0;
  x0 += x1; x1 = rotl32(x1, 6)  ^ x0;
  x0 += ks0; x1 += ks1 + 3u;
  x0 += x1; x1 = rotl32(x1, 17) ^ x0;
  x0 += x1; x1 = rotl32(x1, 29) ^ x0;
  x0 += x1; x1 = rotl32(x1, 16) ^ x0;
  x0 += x1; x1 = rotl32(x1, 24) ^ x0;
  x0 += ks1; x1 += ks2 + 4u;
  x0 += x1; x1 = rotl32(x1, 13) ^ x0;
  x0 += x1; x1 = rotl32(x1, 15) ^ x0;
  x0 += x1; x1 = rotl32(x1, 26) ^ x0;
  x0 += x1; x1 = rotl32(x1, 6)  ^ x0;
  x0 += ks2; x1 += ks0 + 5u;

  const float* mu = dout + OUT_MU;
  const float* lv = dout + OUT_LV;
  const float lo = -0.99999994f;
#pragma unroll
  for (int half = 0; half < 2; ++half) {
    const uint32_t bits = half ? x1 : x0;
    const int e = half ? (p + 1536) : p;
    const float f = __builtin_bit_cast(float, (bits >> 9) | 0x3F800000u) - 1.0f;
    const float u = fmaxf(lo, fmaf(f, 2.0f, lo));
    const float eps = 1.41421356f * erfinv32(u);
    z[e] = fmaf(eps, expf(0.5f * lv[e]), mu[e]);
  }
}

// ---------------------------------------------------------------------------
// XW[b,r,:] = input[b,r,:] @ Wi_d.T + bi_d
// ---------------------------------------------------------------------------
__global__ __launch_bounds__(192) void dec_xw(const float* __restrict__ input,
                                              const float* __restrict__ Wi,
                                              const float* __restrict__ bi,
                                              float* __restrict__ XW) {
  const int br = blockIdx.x;
  __shared__ float xrow[T];
  if (threadIdx.x < T) xrow[threadIdx.x] = input[br * T + threadIdx.x];
  __syncthreads();
  for (int g = threadIdx.x; g < GD; g += 192) {
    const float* w = Wi + g * T;
    float acc = bi[g];
#pragma unroll 8
    for (int d = 0; d < T; ++d) acc = fmaf(w[d], xrow[d], acc);
    XW[br * GD + g] = acc;
  }
}

__global__ __launch_bounds__(256) void wh_to_f16(const float* __restrict__ w,
                                                 _Float16* __restrict__ o) {
  const int i = blockIdx.x * 256 + threadIdx.x;
  if (i < GD * HD) o[i] = (_Float16)w[i];
}

// ---------------------------------------------------------------------------
// Decoder. 768 threads = 12 waves; wave w owns gate tiles {w, 12+w, 24+w},
// i.e. the r/z/n gates for h-range [16w, 16w+16). After the MFMAs (A = h
// broadcast -> all D rows identical) every lane holds the r/z/n preacts for
// h = 16w + (lane&15) in acc registers: gates in-register, 1 barrier/step.
// ---------------------------------------------------------------------------
__global__ __launch_bounds__(768) void decoder(
    const float* __restrict__ XW, const _Float16* __restrict__ WhH,
    const float* __restrict__ bh, const float* __restrict__ z,
    const float* __restrict__ Wl, const float* __restrict__ bl,
    float* __restrict__ dout) {
  const int b = blockIdx.x;
  const int tid = threadIdx.x;
  const int lane = tid & 63;
  const int w = tid >> 6;       // wave 0..11
  const int col = lane & 15;
  const int g4 = lane >> 4;
  const int hidx = 16 * w + col;  // this lane's h index

  __shared__ alignas(16) _Float16 hb[2][HD];  // f16 h, double-buffered
  __shared__ alignas(16) float hf[HD];        // f32 h for the output head

  // B fragments: Wh rows for gates hidx (r), HD+hidx (z), 2*HD+hidx (n).
  // frag[kk] = Wh[gate][32kk + 8*g4 + j], j=0..7 (16B aligned).
  half8 bR[6], bZ[6], bN[6];
#pragma unroll
  for (int kk = 0; kk < 6; ++kk) {
    const int ko = 32 * kk + 8 * g4;
    bR[kk] = *reinterpret_cast<const half8*>(WhH + hidx * HD + ko);
    bZ[kk] = *reinterpret_cast<const half8*>(WhH + (HD + hidx) * HD + ko);
    bN[kk] = *reinterpret_cast<const half8*>(WhH + (2 * HD + hidx) * HD + ko);
  }
  const float bhr = bh[hidx];
  const float bhz = bh[HD + hidx];
  const float bhn = bh[2 * HD + hidx];

  float hold = z[b * HD + hidx];  // this lane's h value (kept in register)
  if (g4 == 0) hb[0][hidx] = (_Float16)hold;
  __syncthreads();

  int cur = 0;
  const float* xwb = XW + b * T * GD;

  for (int i = 0; i < T; ++i) {
    for (int s = 0; s < SD; ++s) {
      const int rr = s + (s >= i ? 1 : 0);
      const float* xwrow = xwb + rr * GD;
      // x-gates: issued early, consumed after MFMAs (covered by ~1000cy)
      const float xr = xwrow[hidx];
      const float xz = xwrow[HD + hidx];
      const float xn = xwrow[2 * HD + hidx];

      // A fragments: h broadcast; same address for all 16 lanes of a group
      half8 a[6];
#pragma unroll
      for (int kk = 0; kk < 6; ++kk)
        a[kk] = *reinterpret_cast<const half8*>(&hb[cur][32 * kk + 8 * g4]);

      // K-split accumulator pairs, bias preloaded into C operand
      f32x4 aR0 = {bhr, bhr, bhr, bhr}, aR1 = {0.f, 0.f, 0.f, 0.f};
      f32x4 aZ0 = {bhz, bhz, bhz, bhz}, aZ1 = {0.f, 0.f, 0.f, 0.f};
      f32x4 aN0 = {bhn, bhn, bhn, bhn}, aN1 = {0.f, 0.f, 0.f, 0.f};
#pragma unroll
      for (int kk = 0; kk < 3; ++kk) {
        aR0 = __builtin_amdgcn_mfma_f32_16x16x32_f16(a[kk], bR[kk], aR0, 0, 0, 0);
        aZ0 = __builtin_amdgcn_mfma_f32_16x16x32_f16(a[kk], bZ[kk], aZ0, 0, 0, 0);
        aN0 = __builtin_amdgcn_mfma_f32_16x16x32_f16(a[kk], bN[kk], aN0, 0, 0, 0);
        aR1 = __builtin_amdgcn_mfma_f32_16x16x32_f16(a[kk + 3], bR[kk + 3], aR1, 0, 0, 0);
        aZ1 = __builtin_amdgcn_mfma_f32_16x16x32_f16(a[kk + 3], bZ[kk + 3], aZ1, 0, 0, 0);
        aN1 = __builtin_amdgcn_mfma_f32_16x16x32_f16(a[kk + 3], bN[kk + 3], aN1, 0, 0, 0);
      }
      // every lane: rows identical -> component 0 is the preact for hidx
      const float pr = aR0[0] + aR1[0];
      const float pz = aZ0[0] + aZ1[0];
      const float pn = aN0[0] + aN1[0];

      const float r  = fsig(xr + pr);
      const float zg = fsig(xz + pz);
      const float n  = ftanh(fmaf(r, pn, xn));
      hold = fmaf(zg, hold - n, n);

      if (g4 == 0) {
        hb[cur ^ 1][hidx] = (_Float16)hold;
        if (s == SD - 1) hf[hidx] = hold;
      }
      __syncthreads();
      cur ^= 1;
    }
    // out_i = h @ Wl.T + bl ; runs concurrently with next step's MFMA phase
    // (hf is only rewritten at s==94, many barriers later)
    if (tid < T) {
      const float4* wl = reinterpret_cast<const float4*>(Wl + tid * HD);
      const float4* hv = reinterpret_cast<const float4*>(hf);
      float a0 = bl[tid], a1 = 0.f, a2 = 0.f, a3 = 0.f;
#pragma unroll
      for (int k = 0; k < HD / 4; k += 4) {
        float4 w0 = wl[k], h0 = hv[k];
        float4 w1 = wl[k + 1], h1 = hv[k + 1];
        float4 w2 = wl[k + 2], h2 = hv[k + 2];
        float4 w3 = wl[k + 3], h3 = hv[k + 3];
        a0 = fmaf(w0.x, h0.x, fmaf(w0.y, h0.y, fmaf(w0.z, h0.z, fmaf(w0.w, h0.w, a0))));
        a1 = fmaf(w1.x, h1.x, fmaf(w1.y, h1.y, fmaf(w1.z, h1.z, fmaf(w1.w, h1.w, a1))));
        a2 = fmaf(w2.x, h2.x, fmaf(w2.y, h2.y, fmaf(w2.z, h2.z, fmaf(w2.w, h2.w, a2))));
        a3 = fmaf(w3.x, h3.x, fmaf(w3.y, h3.y, fmaf(w3.z, h3.z, fmaf(w3.w, h3.w, a3))));
      }
      dout[(b * T + i) * T + tid] = (a0 + a1) + (a2 + a3);
    }
  }
}

}  // namespace

// ---------------------------------------------------------------------------
extern "C" void kernel_launch(void* const* d_in, const int* in_sizes, int n_in,
                              void* d_out, int out_size, void* d_ws,
                              size_t ws_size, hipStream_t stream) {
  const float* input  = (const float*)d_in[0];
  const float* Wc1    = (const float*)d_in[1];
  const float* bc1    = (const float*)d_in[2];
  const float* Wc2    = (const float*)d_in[3];
  const float* bc2    = (const float*)d_in[4];
  const float* Wi_muf = (const float*)d_in[5];
  const float* Wh_muf = (const float*)d_in[6];
  const float* bi_muf = (const float*)d_in[7];
  const float* bh_muf = (const float*)d_in[8];
  const float* Wi_mub = (const float*)d_in[9];
  const float* Wh_mub = (const float*)d_in[10];
  const float* bi_mub = (const float*)d_in[11];
  const float* bh_mub = (const float*)d_in[12];
  const float* Wi_sgf = (const float*)d_in[13];
  const float* Wh_sgf = (const float*)d_in[14];
  const float* bi_sgf = (const float*)d_in[15];
  const float* bh_sgf = (const float*)d_in[16];
  const float* Wi_sgb = (const float*)d_in[17];
  const float* Wh_sgb = (const float*)d_in[18];
  const float* bi_sgb = (const float*)d_in[19];
  const float* bh_sgb = (const float*)d_in[20];
  const float* Wi_d   = (const float*)d_in[21];
  const float* Wh_d   = (const float*)d_in[22];
  const float* bi_d   = (const float*)d_in[23];
  const float* bh_d   = (const float*)d_in[24];
  const float* Wl     = (const float*)d_in[25];
  const float* bl     = (const float*)d_in[26];

  float* ws = (float*)d_ws;
  float* h_enc = ws + WS_HENC;
  float* zbuf  = ws + WS_Z;
  float* XW    = ws + WS_XW;
  _Float16* WhH = (_Float16*)(ws + WS_WHH);
  float* out = (float*)d_out;

  enc_conv<<<B, 256, 0, stream>>>(input, Wc1, bc1, Wc2, bc2, h_enc);
  enc_gru<<<64, 320, 0, stream>>>(h_enc, Wi_muf, Wh_muf, bi_muf, bh_muf,
                                  Wi_mub, Wh_mub, bi_mub, bh_mub,
                                  Wi_sgf, Wh_sgf, bi_sgf, bh_sgf,
                                  Wi_sgb, Wh_sgb, bi_sgb, bh_sgb, out);
  z_kernel<<<6, 256, 0, stream>>>(out, zbuf);
  dec_xw<<<B * T, 192, 0, stream>>>(input, Wi_d, bi_d, XW);
  wh_to_f16<<<(GD * HD + 255) / 256, 256, 0, stream>>>(Wh_d, WhH);
  decoder<<<B, 768, 0, stream>>>(XW, WhH, bh_d, zbuf, Wl, bl, out);
}